// Round 3
// baseline (263.089 us; speedup 1.0000x reference)
//
#include <hip/hip_runtime.h>
#include <hip/hip_bf16.h>
#include <math.h>

#define BB 4
#define LL 8192
#define DD 512
#define HH 8
#define MM (BB*LL)      // 32768
#define NQKV 1536
#define S2 32           // L-splits for kv partial reduction

typedef __attribute__((ext_vector_type(4))) float f32x4;
typedef __attribute__((ext_vector_type(8))) short s16x8;
typedef __attribute__((ext_vector_type(4))) short s16x4;

__device__ __forceinline__ float bf2f(short u) {
  union { unsigned int i; float f; } c;
  c.i = ((unsigned int)(unsigned short)u) << 16;
  return c.f;
}
__device__ __forceinline__ short f2bf(float f) {
  union { float f; unsigned int i; } c; c.f = f;
  unsigned int r = c.i + 0x7FFFu + ((c.i >> 16) & 1u);
  return (short)(r >> 16);
}

__device__ __forceinline__ void gload16(const void* g, void* l) {
  __builtin_amdgcn_global_load_lds(
      (const __attribute__((address_space(1))) void*)(g),
      (__attribute__((address_space(3))) void*)(l), 16, 0, 0);
}

// ---------------- conversion kernels ----------------
__global__ void conv_bf16(const float* __restrict__ in, short* __restrict__ out, int n) {
  int i = (blockIdx.x * blockDim.x + threadIdx.x) * 4;
  if (i < n) {
    float4 v = *reinterpret_cast<const float4*>(in + i);
    s16x4 o;
    o[0] = f2bf(v.x); o[1] = f2bf(v.y); o[2] = f2bf(v.z); o[3] = f2bf(v.w);
    *reinterpret_cast<s16x4*>(out + i) = o;
  }
}

// w[K][N] (row-major) -> wt[N][K] bf16
__global__ void conv_wt(const float* __restrict__ w, short* __restrict__ wt, int K, int N) {
  int idx = blockIdx.x * blockDim.x + threadIdx.x;
  if (idx < K * N) {
    int n = idx / K, k = idx - n * K;
    wt[idx] = f2bf(w[(size_t)k * N + n]);
  }
}

// ---------------- 256x256 phase-interleaved bf16 MFMA GEMM ----------------
// C = A @ BT^T + bias.  A:[M][512], BT:[N][512] bf16.  512 thr = 8 waves (2Mx4N),
// per-wave 128x64 out.  K-tiles BK=32 in a 4-slot rolling LDS buffer (128 KB).
// Swizzle: LDS slot (row, c16) holds global col16 (c16 ^ ((row>>1)&3)); involution,
// applied on the global source address (gload_lds dest stays linear) and on reads.
// MODE 0: bias + phi(col<1024) -> bf16, stride NDIM.  MODE 1: bias -> fp32.
template<int NDIM, int MODE>
__global__ __launch_bounds__(512)
void gemm8(const short* __restrict__ A, const short* __restrict__ BT,
           const float* __restrict__ bias, void* __restrict__ Cout)
{
  constexpr int KD = 512;
  constexpr int NT = 16;             // K-tiles of BK=32
  __shared__ char lds[131072];       // 4 slots x (A 16KB + B 16KB)

  const int tid = threadIdx.x;
  const int wv = tid >> 6, lane = tid & 63;
  const int wm = wv >> 2, wn = wv & 3;

  // XCD-aware block swizzle (grid counts divisible by 8)
  const int gx = gridDim.x;
  int id = blockIdx.y * gx + blockIdx.x;
  const int nwg = gx * gridDim.y;
  id = (id & 7) * (nwg >> 3) + (id >> 3);
  const int bx = id % gx, by = id / gx;
  const int m0 = bx * 256, n0 = by * 256;

  // staging constants: issue i covers rows i*128 + wv*16 + (lane>>2), c16 = lane&3
  const int srow = wv * 16 + (lane >> 2);
  const int scol = ((lane & 3) ^ ((lane >> 3) & 3)) * 8;   // pre-swizzled global col
  const short* Ag = A  + (size_t)(m0 + srow) * KD + scol;
  const short* Bg = BT + (size_t)(n0 + srow) * KD + scol;
  char* ldsw = lds + wv * 1024;      // + lane*16 implicit in gload_lds

  auto stageA = [&](int tn, int i) {
    gload16(Ag + ((size_t)i * 128) * KD + tn * 32,
            ldsw + (tn & 3) * 32768 + i * 8192);
  };
  auto stageB = [&](int tn, int i) {
    gload16(Bg + ((size_t)i * 128) * KD + tn * 32,
            ldsw + (tn & 3) * 32768 + 16384 + i * 8192);
  };

  // fragment-read constants
  const int fr = lane & 15, f16 = lane >> 4;
  const int sel = (f16 ^ ((fr >> 1) & 3)) * 16;            // swizzled 16B slot
  const char* ldsA = lds + (wm * 128 + fr) * 64 + sel;
  const char* ldsB = lds + 16384 + (wn * 64 + fr) * 64 + sel;

  // prologue: stage tiles 0 and 1
#pragma unroll
  for (int tn = 0; tn < 2; ++tn) {
    stageA(tn, 0); stageA(tn, 1); stageB(tn, 0); stageB(tn, 1);
  }
  asm volatile("s_waitcnt vmcnt(4)" ::: "memory");   // tile 0 landed
  __builtin_amdgcn_s_barrier();

  f32x4 acc[8][4] = {};
  s16x8 bfr[4];

  for (int it = 0; it < NT; ++it) {
    const int slot = (it & 3) * 32768;
    const int tn = it + 2;
    const bool st = tn < NT;
#pragma unroll
    for (int q = 0; q < 4; ++q) {
      s16x8 afr[2];
      if (q == 0) {
#pragma unroll
        for (int j = 0; j < 4; ++j)
          bfr[j] = *(const s16x8*)(ldsB + slot + j * 1024);
      }
#pragma unroll
      for (int mi = 0; mi < 2; ++mi)
        afr[mi] = *(const s16x8*)(ldsA + slot + (q * 32 + mi * 16) * 64);
      if (st) {
        if (q == 0)      stageA(tn, 0);
        else if (q == 1) stageA(tn, 1);
        else if (q == 2) stageB(tn, 0);
        else             stageB(tn, 1);
      }
      __builtin_amdgcn_s_barrier();
      __builtin_amdgcn_s_setprio(1);
#pragma unroll
      for (int mi = 0; mi < 2; ++mi)
#pragma unroll
        for (int j = 0; j < 4; ++j)
          acc[q * 2 + mi][j] = __builtin_amdgcn_mfma_f32_16x16x32_bf16(
              afr[mi], bfr[j], acc[q * 2 + mi][j], 0, 0, 0);
      __builtin_amdgcn_s_setprio(0);
      if (q == 3) {   // gate next iteration's reads: tile it+1 must be resident
        if (it < NT - 2)
          asm volatile("s_waitcnt vmcnt(4)" ::: "memory");
        else
          asm volatile("s_waitcnt vmcnt(0)" ::: "memory");
      }
      __builtin_amdgcn_s_barrier();
    }
  }

  // epilogue: C/D layout col = lane&15, row = (lane>>4)*4 + reg
  const int crow0 = m0 + wm * 128;
  const int ccol0 = n0 + wn * 64;
#pragma unroll
  for (int j = 0; j < 4; ++j) {
    const int col = ccol0 + j * 16 + fr;
    const float bv = bias[col];
#pragma unroll
    for (int qm = 0; qm < 8; ++qm) {
      const int rbase = crow0 + qm * 16 + f16 * 4;
#pragma unroll
      for (int r = 0; r < 4; ++r) {
        float v = acc[qm][j][r] + bv;
        if (MODE == 0) {
          if (col < 1024) v = (v > 0.f) ? (v + 1.f) : __expf(v);  // phi = elu+1
          ((short*)Cout)[(size_t)(rbase + r) * NDIM + col] = f2bf(v);
        } else {
          ((float*)Cout)[(size_t)(rbase + r) * NDIM + col] = v;
        }
      }
    }
  }
}

// ---------------- kv / ksum partial reduction ----------------
__global__ __launch_bounds__(256, 4)
void kv_partial(const short* __restrict__ qkv_b, float* __restrict__ pkv, float* __restrict__ pks)
{
  const int head = blockIdx.x;   // b*H + h, 0..31
  const int split = blockIdx.y;  // 0..S2-1
  const int b = head >> 3, h = head & 7;
  const int tid = threadIdx.x, wv = tid >> 6, d = tid & 63;
  const short* kb = qkv_b + (size_t)b * LL * NQKV + 512 + h * 64;
  const short* vb = qkv_b + (size_t)b * LL * NQKV + 1024 + h * 64 + wv * 16;
  float acc[16];
#pragma unroll
  for (int j = 0; j < 16; ++j) acc[j] = 0.f;
  float ks = 0.f;
  const int l0 = split * (LL / S2);
  for (int li = 0; li < LL / S2; ++li) {
    const size_t ro = (size_t)(l0 + li) * NQKV;
    const float kd = bf2f(kb[ro + d]);
    ks += kd;
    s16x8 v0 = *(const s16x8*)(vb + ro);
    s16x8 v1 = *(const s16x8*)(vb + ro + 8);
#pragma unroll
    for (int j = 0; j < 8; ++j) acc[j] = fmaf(bf2f(v0[j]), kd, acc[j]);
#pragma unroll
    for (int j = 0; j < 8; ++j) acc[8 + j] = fmaf(bf2f(v1[j]), kd, acc[8 + j]);
  }
  float* o = pkv + ((size_t)head * S2 + split) * 4096 + d;
#pragma unroll
  for (int j = 0; j < 16; ++j) o[(wv * 16 + j) * 64] = acc[j];
  if (wv == 0) pks[((size_t)head * S2 + split) * 64 + d] = ks;
}

// reduce partials -> bf16 kv_b [head][m][d], bf16 ksum_b [head][d] (with +1e-6)
__global__ void kv_reduce(const float* __restrict__ pkv, const float* __restrict__ pks,
                          short* __restrict__ kv_b, short* __restrict__ ksum_b)
{
  const int idx = blockIdx.x * 256 + threadIdx.x;   // head*4096 + m*64 + d
  const int head = idx >> 12, md = idx & 4095;
  float s = 0.f;
  for (int i = 0; i < S2; ++i) s += pkv[((size_t)head * S2 + i) * 4096 + md];
  kv_b[idx] = f2bf(s);
  if (md < 64) {
    float t = 0.f;
    for (int i = 0; i < S2; ++i) t += pks[((size_t)head * S2 + i) * 64 + md];
    ksum_b[head * 64 + md] = f2bf(t + 1e-6f);
  }
}

// ---------------- attn via MFMA: attn[l][m] = (q_l . kv[m]) / (q_l . ksum) ----------------
__global__ __launch_bounds__(256, 2)
void attn_mfma(const short* __restrict__ qkv_b, const short* __restrict__ kv_b,
               const short* __restrict__ ksum_b, short* __restrict__ attn)
{
  const int hb = blockIdx.x;     // 0..31 (b*H + h)
  const int tile = blockIdx.y;   // 0..31 (256 rows each)
  const int b = hb >> 3, h = hb & 7;
  const int tid = threadIdx.x, wv = tid >> 6, lane = tid & 63;
  const int fr = lane & 15, fk = (lane >> 4) * 8;

  const short* kvp = kv_b + (size_t)hb * 4096;
  s16x8 bfrag[4][2];
#pragma unroll
  for (int j = 0; j < 4; ++j)
#pragma unroll
    for (int kk = 0; kk < 2; ++kk)
      bfrag[j][kk] = *(const s16x8*)(kvp + (j * 16 + fr) * 64 + kk * 32 + fk);
  s16x8 bden[2];
#pragma unroll
  for (int kk = 0; kk < 2; ++kk)
    bden[kk] = *(const s16x8*)(ksum_b + hb * 64 + kk * 32 + fk);

  const short* qb = qkv_b + (size_t)b * LL * NQKV + h * 64;
  const int l0 = tile * 256 + wv * 64;
  f32x4 accn[4][4] = {};
  f32x4 accd[4] = {};
#pragma unroll
  for (int i = 0; i < 4; ++i) {
#pragma unroll
    for (int kk = 0; kk < 2; ++kk) {
      s16x8 a = *(const s16x8*)(qb + (size_t)(l0 + i * 16 + fr) * NQKV + kk * 32 + fk);
      accd[i] = __builtin_amdgcn_mfma_f32_16x16x32_bf16(a, bden[kk], accd[i], 0, 0, 0);
#pragma unroll
      for (int j = 0; j < 4; ++j)
        accn[i][j] = __builtin_amdgcn_mfma_f32_16x16x32_bf16(a, bfrag[j][kk], accn[i][j], 0, 0, 0);
    }
  }

  short* ob = attn + (size_t)b * LL * DD + h * 64;
  const int fq = lane >> 4;
#pragma unroll
  for (int i = 0; i < 4; ++i) {
#pragma unroll
    for (int r = 0; r < 4; ++r) {
      const int row = l0 + i * 16 + fq * 4 + r;
      const float dinv = 1.0f / accd[i][r];
#pragma unroll
      for (int j = 0; j < 4; ++j) {
        ob[(size_t)row * DD + j * 16 + fr] = f2bf(accn[i][j][r] * dinv);
      }
    }
  }
}

// ---------------- launch ----------------
extern "C" void kernel_launch(void* const* d_in, const int* in_sizes, int n_in,
                              void* d_out, int out_size, void* d_ws, size_t ws_size,
                              hipStream_t stream)
{
  const float* x     = (const float*)d_in[0];
  const float* w_qkv = (const float*)d_in[1];
  const float* b_qkv = (const float*)d_in[2];
  const float* w_out = (const float*)d_in[3];
  const float* b_out = (const float*)d_in[4];

  char* ws = (char*)d_ws;
  size_t off = 0;
  short* x_b   = (short*)(ws + off); off += (size_t)MM * DD * 2;        // 32 MB
  short* wq_t  = (short*)(ws + off); off += (size_t)NQKV * DD * 2;      // 1.5 MB
  short* wo_t  = (short*)(ws + off); off += (size_t)DD * DD * 2;        // 0.5 MB
  short* qkv_b = (short*)(ws + off); off += (size_t)MM * NQKV * 2;      // 96 MB
  short* attn_b= (short*)(ws + off); off += (size_t)MM * DD * 2;        // 32 MB
  float* pkv   = (float*)(ws + off); off += (size_t)32 * S2 * 4096 * 4; // 16 MB
  float* pks   = (float*)(ws + off); off += (size_t)32 * S2 * 64 * 4;   // 0.5 MB
  short* kv_b  = (short*)(ws + off); off += (size_t)32 * 4096 * 2;      // 0.25 MB
  short* ksum_b= (short*)(ws + off); off += (size_t)32 * 64 * 2;        // 4 KB

  conv_bf16<<<dim3((MM * DD / 4 + 255) / 256), dim3(256), 0, stream>>>(x, x_b, MM * DD);
  conv_wt<<<dim3((DD * NQKV + 255) / 256), dim3(256), 0, stream>>>(w_qkv, wq_t, DD, NQKV);
  conv_wt<<<dim3((DD * DD + 255) / 256), dim3(256), 0, stream>>>(w_out, wo_t, DD, DD);

  // qkv = x @ w_qkv + b; phi on q,k; bf16 store
  gemm8<NQKV, 0><<<dim3(MM / 256, NQKV / 256), dim3(512), 0, stream>>>(
      x_b, wq_t, b_qkv, (void*)qkv_b);

  kv_partial<<<dim3(32, S2), dim3(256), 0, stream>>>(qkv_b, pkv, pks);
  kv_reduce<<<dim3(512), dim3(256), 0, stream>>>(pkv, pks, kv_b, ksum_b);

  attn_mfma<<<dim3(32, 32), dim3(256), 0, stream>>>(qkv_b, kv_b, ksum_b, attn_b);

  // out = attn @ w_out + b_out (fp32)
  gemm8<DD, 1><<<dim3(MM / 256, DD / 256), dim3(512), 0, stream>>>(
      attn_b, wo_t, b_out, d_out);
}

// Round 4
// 245.690 us; speedup vs baseline: 1.0708x; 1.0708x over previous
//
#include <hip/hip_runtime.h>
#include <hip/hip_bf16.h>
#include <math.h>

#define BB 4
#define LL 8192
#define DD 512
#define HH 8
#define MM (BB*LL)      // 32768
#define NQKV 1536
#define S2 32           // L-splits for kv partial reduction

typedef __attribute__((ext_vector_type(4))) float f32x4;
typedef __attribute__((ext_vector_type(8))) short s16x8;
typedef __attribute__((ext_vector_type(4))) short s16x4;

__device__ __forceinline__ float bf2f(short u) {
  union { unsigned int i; float f; } c;
  c.i = ((unsigned int)(unsigned short)u) << 16;
  return c.f;
}
__device__ __forceinline__ short f2bf(float f) {
  union { float f; unsigned int i; } c; c.f = f;
  unsigned int r = c.i + 0x7FFFu + ((c.i >> 16) & 1u);
  return (short)(r >> 16);
}

__device__ __forceinline__ void gload16(const void* g, void* l) {
  __builtin_amdgcn_global_load_lds(
      (const __attribute__((address_space(1))) void*)(g),
      (__attribute__((address_space(3))) void*)(l), 16, 0, 0);
}

// ---------------- conversion kernels ----------------
__global__ void conv_bf16(const float* __restrict__ in, short* __restrict__ out, int n) {
  int i = (blockIdx.x * blockDim.x + threadIdx.x) * 4;
  if (i < n) {
    float4 v = *reinterpret_cast<const float4*>(in + i);
    s16x4 o;
    o[0] = f2bf(v.x); o[1] = f2bf(v.y); o[2] = f2bf(v.z); o[3] = f2bf(v.w);
    *reinterpret_cast<s16x4*>(out + i) = o;
  }
}

// w[K][N] (row-major) -> wt[N][K] bf16
__global__ void conv_wt(const float* __restrict__ w, short* __restrict__ wt, int K, int N) {
  int idx = blockIdx.x * blockDim.x + threadIdx.x;
  if (idx < K * N) {
    int n = idx / K, k = idx - n * K;
    wt[idx] = f2bf(w[(size_t)k * N + n]);
  }
}

// ---------------- bf16 MFMA GEMM, C = A @ BT^T + bias ----------------
// 128x128 tile, BK=64, 4 waves, single-buffered LDS (32 KB) -> multi-block/CU.
// LDS swizzle: row r, 16B-unit u stored at unit (u ^ (r&7)); applied on the
// global source of global_load_lds (pre-swizzle) and on fragment reads.
// Epilogue staged through LDS for coalesced 16B stores.
// MODE 0: bias + phi (block-uniform: n0<1024) -> bf16.  MODE 1: bias -> fp32.
template<int NDIM, int MODE>
__global__ __launch_bounds__(256, 2)
void gemm_bt(const short* __restrict__ A, const short* __restrict__ BT,
             const float* __restrict__ bias, void* __restrict__ Cout)
{
  constexpr int KD = 512;
  __shared__ __align__(16) char lds[32768];   // As 16KB | Bs 16KB; reused by epilogue
  short* As = (short*)lds;
  short* Bs = (short*)(lds + 16384);

  const int tid = threadIdx.x;
  const int wv = tid >> 6, lane = tid & 63;
  const int wm = (wv >> 1) * 64, wn = (wv & 1) * 64;
  const int fr = lane & 15, fq = lane >> 4;

  // XCD-chunked block swizzle (nwg % 8 == 0 for all our grids)
  const int gx = gridDim.x;
  int id = blockIdx.y * gx + blockIdx.x;
  const int nwg = gx * gridDim.y;
  id = (id & 7) * (nwg >> 3) + (id >> 3);
  const int m0 = (id % gx) * 128, n0 = (id / gx) * 128;

  // staging: issue i covers rows i*32 + (tid>>3); LDS unit u' = tid&7 holds
  // global unit u = u' ^ (row&7)
  const int srow = tid >> 3;
  const int sunit = (tid & 7) ^ (srow & 7);
  const short* Ag = A  + (size_t)(m0 + srow) * KD + sunit * 8;
  const short* Bg = BT + (size_t)(n0 + srow) * KD + sunit * 8;
  char* ldsA = (char*)As + wv * 1024;
  char* ldsB = (char*)Bs + wv * 1024;

  f32x4 acc[4][4] = {};

  for (int k0 = 0; k0 < KD; k0 += 64) {
#pragma unroll
    for (int i = 0; i < 4; ++i) {
      gload16(Ag + (size_t)i * 32 * KD + k0, ldsA + i * 4096);
      gload16(Bg + (size_t)i * 32 * KD + k0, ldsB + i * 4096);
    }
    __syncthreads();
#pragma unroll
    for (int kk = 0; kk < 2; ++kk) {
      s16x8 af[4], bfg[4];
#pragma unroll
      for (int i = 0; i < 4; ++i) {
        const int ra = wm + i * 16 + fr;
        const int ua = (kk * 4 + fq) ^ (ra & 7);
        af[i] = *(const s16x8*)((const char*)As + ra * 128 + ua * 16);
        const int rb = wn + i * 16 + fr;
        const int ub = (kk * 4 + fq) ^ (rb & 7);
        bfg[i] = *(const s16x8*)((const char*)Bs + rb * 128 + ub * 16);
      }
#pragma unroll
      for (int i = 0; i < 4; ++i)
#pragma unroll
        for (int j = 0; j < 4; ++j)
          acc[i][j] = __builtin_amdgcn_mfma_f32_16x16x32_bf16(af[i], bfg[j], acc[i][j], 0, 0, 0);
    }
    __syncthreads();
  }

  // ---- epilogue through LDS (coalesced 16B global stores) ----
  if (MODE == 0) {
    short* scr = (short*)lds;   // 128x128 bf16 = 32KB
    const bool do_phi = (n0 < 1024);
#pragma unroll
    for (int j = 0; j < 4; ++j) {
      const float bv = bias[n0 + wn + j * 16 + fr];
#pragma unroll
      for (int i = 0; i < 4; ++i) {
        const int row = wm + i * 16 + fq * 4;
#pragma unroll
        for (int r = 0; r < 4; ++r) {
          float v = acc[i][j][r] + bv;
          if (do_phi) v = (v > 0.f) ? (v + 1.f) : __expf(v);   // phi = elu+1
          scr[(row + r) * 128 + wn + j * 16 + fr] = f2bf(v);
        }
      }
    }
    __syncthreads();
#pragma unroll
    for (int p = 0; p < 8; ++p) {
      const int off = p * 4096 + tid * 16;          // bytes
      const int row = off >> 8, colb = off & 255;   // 256B per row
      s16x8 v = *(const s16x8*)(lds + off);
      *(s16x8*)((short*)Cout + (size_t)(m0 + row) * NDIM + n0 + (colb >> 1)) = v;
    }
  } else {
    float* scrf = (float*)lds;  // 64x128 fp32 = 32KB per half
#pragma unroll
    for (int h = 0; h < 2; ++h) {
      __syncthreads();
      if ((wv >> 1) == h) {
#pragma unroll
        for (int j = 0; j < 4; ++j) {
          const float bv = bias[n0 + wn + j * 16 + fr];
#pragma unroll
          for (int i = 0; i < 4; ++i) {
            const int row = i * 16 + fq * 4;
#pragma unroll
            for (int r = 0; r < 4; ++r)
              scrf[(row + r) * 128 + wn + j * 16 + fr] = acc[i][j][r] + bv;
          }
        }
      }
      __syncthreads();
#pragma unroll
      for (int p = 0; p < 8; ++p) {
        const int off = p * 4096 + tid * 16;
        const int row = off >> 9, colb = off & 511;   // 512B per row
        float4 v = *(const float4*)(lds + off);
        *(float4*)((float*)Cout + (size_t)(m0 + h * 64 + row) * NDIM + n0 + (colb >> 2)) = v;
      }
    }
  }
}

// ---------------- kv / ksum partial reduction ----------------
__global__ __launch_bounds__(256, 4)
void kv_partial(const short* __restrict__ qkv_b, float* __restrict__ pkv, float* __restrict__ pks)
{
  const int head = blockIdx.x;   // b*H + h, 0..31
  const int split = blockIdx.y;  // 0..S2-1
  const int b = head >> 3, h = head & 7;
  const int tid = threadIdx.x, wv = tid >> 6, d = tid & 63;
  const short* kb = qkv_b + (size_t)b * LL * NQKV + 512 + h * 64;
  const short* vb = qkv_b + (size_t)b * LL * NQKV + 1024 + h * 64 + wv * 16;
  float acc[16];
#pragma unroll
  for (int j = 0; j < 16; ++j) acc[j] = 0.f;
  float ks = 0.f;
  const int l0 = split * (LL / S2);
  for (int li = 0; li < LL / S2; ++li) {
    const size_t ro = (size_t)(l0 + li) * NQKV;
    const float kd = bf2f(kb[ro + d]);
    ks += kd;
    s16x8 v0 = *(const s16x8*)(vb + ro);
    s16x8 v1 = *(const s16x8*)(vb + ro + 8);
#pragma unroll
    for (int j = 0; j < 8; ++j) acc[j] = fmaf(bf2f(v0[j]), kd, acc[j]);
#pragma unroll
    for (int j = 0; j < 8; ++j) acc[8 + j] = fmaf(bf2f(v1[j]), kd, acc[8 + j]);
  }
  float* o = pkv + ((size_t)head * S2 + split) * 4096 + d;
#pragma unroll
  for (int j = 0; j < 16; ++j) o[(wv * 16 + j) * 64] = acc[j];
  if (wv == 0) pks[((size_t)head * S2 + split) * 64 + d] = ks;
}

// reduce partials -> bf16 kv_b [head][m][d], bf16 ksum_b [head][d] (with +1e-6)
__global__ void kv_reduce(const float* __restrict__ pkv, const float* __restrict__ pks,
                          short* __restrict__ kv_b, short* __restrict__ ksum_b)
{
  const int idx = blockIdx.x * 256 + threadIdx.x;   // head*4096 + m*64 + d
  const int head = idx >> 12, md = idx & 4095;
  float s = 0.f;
  for (int i = 0; i < S2; ++i) s += pkv[((size_t)head * S2 + i) * 4096 + md];
  kv_b[idx] = f2bf(s);
  if (md < 64) {
    float t = 0.f;
    for (int i = 0; i < S2; ++i) t += pks[((size_t)head * S2 + i) * 64 + md];
    ksum_b[head * 64 + md] = f2bf(t + 1e-6f);
  }
}

// ---------------- attn via MFMA: attn[l][m] = (q_l . kv[m]) / (q_l . ksum) ----------------
__global__ __launch_bounds__(256, 2)
void attn_mfma(const short* __restrict__ qkv_b, const short* __restrict__ kv_b,
               const short* __restrict__ ksum_b, short* __restrict__ attn)
{
  const int hb = blockIdx.x;     // 0..31 (b*H + h)
  const int tile = blockIdx.y;   // 0..31 (256 rows each)
  const int b = hb >> 3, h = hb & 7;
  const int tid = threadIdx.x, wv = tid >> 6, lane = tid & 63;
  const int fr = lane & 15, fk = (lane >> 4) * 8;

  const short* kvp = kv_b + (size_t)hb * 4096;
  s16x8 bfrag[4][2];
#pragma unroll
  for (int j = 0; j < 4; ++j)
#pragma unroll
    for (int kk = 0; kk < 2; ++kk)
      bfrag[j][kk] = *(const s16x8*)(kvp + (j * 16 + fr) * 64 + kk * 32 + fk);
  s16x8 bden[2];
#pragma unroll
  for (int kk = 0; kk < 2; ++kk)
    bden[kk] = *(const s16x8*)(ksum_b + hb * 64 + kk * 32 + fk);

  const short* qb = qkv_b + (size_t)b * LL * NQKV + h * 64;
  const int l0 = tile * 256 + wv * 64;
  f32x4 accn[4][4] = {};
  f32x4 accd[4] = {};
#pragma unroll
  for (int i = 0; i < 4; ++i) {
#pragma unroll
    for (int kk = 0; kk < 2; ++kk) {
      s16x8 a = *(const s16x8*)(qb + (size_t)(l0 + i * 16 + fr) * NQKV + kk * 32 + fk);
      accd[i] = __builtin_amdgcn_mfma_f32_16x16x32_bf16(a, bden[kk], accd[i], 0, 0, 0);
#pragma unroll
      for (int j = 0; j < 4; ++j)
        accn[i][j] = __builtin_amdgcn_mfma_f32_16x16x32_bf16(a, bfrag[j][kk], accn[i][j], 0, 0, 0);
    }
  }

  short* ob = attn + (size_t)b * LL * DD + h * 64;
  const int fq = lane >> 4;
#pragma unroll
  for (int i = 0; i < 4; ++i) {
#pragma unroll
    for (int r = 0; r < 4; ++r) {
      const int row = l0 + i * 16 + fq * 4 + r;
      const float dinv = 1.0f / accd[i][r];
#pragma unroll
      for (int j = 0; j < 4; ++j) {
        ob[(size_t)row * DD + j * 16 + fr] = f2bf(accn[i][j][r] * dinv);
      }
    }
  }
}

// ---------------- launch ----------------
extern "C" void kernel_launch(void* const* d_in, const int* in_sizes, int n_in,
                              void* d_out, int out_size, void* d_ws, size_t ws_size,
                              hipStream_t stream)
{
  const float* x     = (const float*)d_in[0];
  const float* w_qkv = (const float*)d_in[1];
  const float* b_qkv = (const float*)d_in[2];
  const float* w_out = (const float*)d_in[3];
  const float* b_out = (const float*)d_in[4];

  char* ws = (char*)d_ws;
  size_t off = 0;
  short* x_b   = (short*)(ws + off); off += (size_t)MM * DD * 2;        // 32 MB
  short* wq_t  = (short*)(ws + off); off += (size_t)NQKV * DD * 2;      // 1.5 MB
  short* wo_t  = (short*)(ws + off); off += (size_t)DD * DD * 2;        // 0.5 MB
  short* qkv_b = (short*)(ws + off); off += (size_t)MM * NQKV * 2;      // 96 MB
  short* attn_b= (short*)(ws + off); off += (size_t)MM * DD * 2;        // 32 MB
  float* pkv   = (float*)(ws + off); off += (size_t)32 * S2 * 4096 * 4; // 16 MB
  float* pks   = (float*)(ws + off); off += (size_t)32 * S2 * 64 * 4;   // 0.5 MB
  short* kv_b  = (short*)(ws + off); off += (size_t)32 * 4096 * 2;      // 0.25 MB
  short* ksum_b= (short*)(ws + off); off += (size_t)32 * 64 * 2;        // 4 KB

  conv_bf16<<<dim3((MM * DD / 4 + 255) / 256), dim3(256), 0, stream>>>(x, x_b, MM * DD);
  conv_wt<<<dim3((DD * NQKV + 255) / 256), dim3(256), 0, stream>>>(w_qkv, wq_t, DD, NQKV);
  conv_wt<<<dim3((DD * DD + 255) / 256), dim3(256), 0, stream>>>(w_out, wo_t, DD, DD);

  // qkv = x @ w_qkv + b; phi on q,k; bf16 store
  gemm_bt<NQKV, 0><<<dim3(MM / 128, NQKV / 128), dim3(256), 0, stream>>>(
      x_b, wq_t, b_qkv, (void*)qkv_b);

  kv_partial<<<dim3(32, S2), dim3(256), 0, stream>>>(qkv_b, pkv, pks);
  kv_reduce<<<dim3(512), dim3(256), 0, stream>>>(pkv, pks, kv_b, ksum_b);

  attn_mfma<<<dim3(32, 32), dim3(256), 0, stream>>>(qkv_b, kv_b, ksum_b, attn_b);

  // out = attn @ w_out + b_out (fp32)
  gemm_bt<DD, 1><<<dim3(MM / 128, DD / 128), dim3(256), 0, stream>>>(
      attn_b, wo_t, b_out, d_out);
}

// Round 5
// 233.269 us; speedup vs baseline: 1.1278x; 1.0533x over previous
//
#include <hip/hip_runtime.h>
#include <hip/hip_bf16.h>
#include <math.h>

#define BB 4
#define LL 8192
#define DD 512
#define HH 8
#define MM (BB*LL)      // 32768
#define NQKV 1536
#define S2 32           // L-splits for kv partial reduction

typedef __attribute__((ext_vector_type(4))) float f32x4;
typedef __attribute__((ext_vector_type(8))) short s16x8;
typedef __attribute__((ext_vector_type(4))) short s16x4;

__device__ __forceinline__ float bf2f(short u) {
  union { unsigned int i; float f; } c;
  c.i = ((unsigned int)(unsigned short)u) << 16;
  return c.f;
}
__device__ __forceinline__ short f2bf(float f) {
  union { float f; unsigned int i; } c; c.f = f;
  unsigned int r = c.i + 0x7FFFu + ((c.i >> 16) & 1u);
  return (short)(r >> 16);
}

__device__ __forceinline__ void gload16(const void* g, void* l) {
  __builtin_amdgcn_global_load_lds(
      (const __attribute__((address_space(1))) void*)(g),
      (__attribute__((address_space(3))) void*)(l), 16, 0, 0);
}

// ---------------- conversion kernels ----------------
__global__ void conv_bf16(const float* __restrict__ in, short* __restrict__ out, int n) {
  int i = (blockIdx.x * blockDim.x + threadIdx.x) * 4;
  if (i < n) {
    float4 v = *reinterpret_cast<const float4*>(in + i);
    s16x4 o;
    o[0] = f2bf(v.x); o[1] = f2bf(v.y); o[2] = f2bf(v.z); o[3] = f2bf(v.w);
    *reinterpret_cast<s16x4*>(out + i) = o;
  }
}

// w[K][N] (row-major) -> wt[N][K] bf16
__global__ void conv_wt(const float* __restrict__ w, short* __restrict__ wt, int K, int N) {
  int idx = blockIdx.x * blockDim.x + threadIdx.x;
  if (idx < K * N) {
    int n = idx / K, k = idx - n * K;
    wt[idx] = f2bf(w[(size_t)k * N + n]);
  }
}

// ---------------- bf16 MFMA GEMM, C = A @ BT^T + bias ----------------
// 256x128 tile (BM=256, BN=128), BK=64, 8 waves (4M x 2N), per-wave 64x64 out.
// Single-buffered LDS 48KB staged + 64KB epilogue scratch -> 2 blocks/CU.
// XCD chunking is M-MAJOR: each XCD owns a contiguous m-stripe (A slice = 4MB
// = its private L2), so A is HBM-fetched ~once.
// LDS swizzle: row r, 16B-unit u stored at (u ^ (r&7)); applied on the global
// source (pre-swizzle) and on fragment reads (involution).
// MODE 0: bias + phi (block-uniform: n0<1024) -> bf16.  MODE 1: bias -> fp32.
template<int NDIM, int MODE>
__global__ __launch_bounds__(512, 4)
void gemm_bt(const short* __restrict__ A, const short* __restrict__ BT,
             const float* __restrict__ bias, void* __restrict__ Cout)
{
  constexpr int KD = 512;
  __shared__ __align__(16) char lds[65536];   // As 32KB | Bs 16KB; epilogue reuses 64KB

  const int tid = threadIdx.x;
  const int wv = tid >> 6, lane = tid & 63;
  const int wm = wv >> 1, wn = wv & 1;        // 4 m-waves x 2 n-waves
  const int fr = lane & 15, fq = lane >> 4;

  // m-major XCD chunking: dispatch index d -> lin; XCD c owns lin-range
  // [c*nwg/8, ...) which is a contiguous m-stripe (m-major decode).
  const int gx = gridDim.x;                   // # m-blocks
  const int gy = gridDim.y;                   // # n-blocks
  const int d = blockIdx.y * gx + blockIdx.x;
  const int nwg = gx * gy;
  const int lin = (d & 7) * (nwg >> 3) + (d >> 3);
  const int m0 = (lin / gy) * 256, n0 = (lin % gy) * 128;

  // staging: issue covers rows (tid>>3) + i*64; LDS unit tid&7 holds global
  // unit (tid&7)^(row&7)
  const int srow = tid >> 3;
  const int sunit = (tid & 7) ^ (srow & 7);
  const short* Ag = A  + (size_t)(m0 + srow) * KD + sunit * 8;
  const short* Bg = BT + (size_t)(n0 + srow) * KD + sunit * 8;
  char* ldsw = lds + wv * 1024;               // + lane*16 implicit in gload_lds

  f32x4 acc[4][4] = {};

  for (int t = 0; t < 8; ++t) {
    const int k0 = t * 64;
#pragma unroll
    for (int i = 0; i < 4; ++i)
      gload16(Ag + (size_t)(i * 64) * KD + k0, ldsw + i * 8192);
#pragma unroll
    for (int i = 0; i < 2; ++i)
      gload16(Bg + (size_t)(i * 64) * KD + k0, ldsw + 32768 + i * 8192);
    __syncthreads();
#pragma unroll
    for (int kk = 0; kk < 2; ++kk) {
      s16x8 af[4], bfg[4];
#pragma unroll
      for (int i = 0; i < 4; ++i) {
        const int ra = wm * 64 + i * 16 + fr;
        const int ua = (kk * 4 + fq) ^ (ra & 7);
        af[i] = *(const s16x8*)(lds + ra * 128 + ua * 16);
      }
#pragma unroll
      for (int j = 0; j < 4; ++j) {
        const int rb = wn * 64 + j * 16 + fr;
        const int ub = (kk * 4 + fq) ^ (rb & 7);
        bfg[j] = *(const s16x8*)(lds + 32768 + rb * 128 + ub * 16);
      }
#pragma unroll
      for (int i = 0; i < 4; ++i)
#pragma unroll
        for (int j = 0; j < 4; ++j)
          acc[i][j] = __builtin_amdgcn_mfma_f32_16x16x32_bf16(af[i], bfg[j], acc[i][j], 0, 0, 0);
    }
    __syncthreads();
  }

  // ---- epilogue through LDS (coalesced 16B global stores) ----
  if (MODE == 0) {
    short* scr = (short*)lds;   // 256x128 bf16 = 64KB
    const bool do_phi = (n0 < 1024);
#pragma unroll
    for (int j = 0; j < 4; ++j) {
      const int col = wn * 64 + j * 16 + fr;
      const float bv = bias[n0 + col];
#pragma unroll
      for (int i = 0; i < 4; ++i) {
        const int row = wm * 64 + i * 16 + fq * 4;
#pragma unroll
        for (int r = 0; r < 4; ++r) {
          float v = acc[i][j][r] + bv;
          if (do_phi) v = (v > 0.f) ? (v + 1.f) : __expf(v);   // phi = elu+1
          scr[(row + r) * 128 + col] = f2bf(v);
        }
      }
    }
    __syncthreads();
#pragma unroll
    for (int p = 0; p < 8; ++p) {
      const int off = p * 8192 + tid * 16;          // bytes
      const int row = off >> 8, colb = off & 255;   // 256B per row
      s16x8 v = *(const s16x8*)(lds + off);
      *(s16x8*)((short*)Cout + (size_t)(m0 + row) * NDIM + n0 + (colb >> 1)) = v;
    }
  } else {
    float* scrf = (float*)lds;  // 128x128 fp32 = 64KB per half
#pragma unroll
    for (int h = 0; h < 2; ++h) {
      __syncthreads();
      if ((wm >> 1) == h) {
#pragma unroll
        for (int j = 0; j < 4; ++j) {
          const int col = wn * 64 + j * 16 + fr;
          const float bv = bias[n0 + col];
#pragma unroll
          for (int i = 0; i < 4; ++i) {
            const int row = (wm & 1) * 64 + i * 16 + fq * 4;
#pragma unroll
            for (int r = 0; r < 4; ++r)
              scrf[(row + r) * 128 + col] = acc[i][j][r] + bv;
          }
        }
      }
      __syncthreads();
#pragma unroll
      for (int p = 0; p < 8; ++p) {
        const int off = p * 8192 + tid * 16;
        const int row = off >> 9, colb = off & 511;   // 512B per row
        float4 v = *(const float4*)(lds + off);
        *(float4*)((float*)Cout + (size_t)(m0 + h * 128 + row) * NDIM + n0 + (colb >> 2)) = v;
      }
    }
  }
}

// ---------------- kv / ksum partial reduction ----------------
__global__ __launch_bounds__(256, 4)
void kv_partial(const short* __restrict__ qkv_b, float* __restrict__ pkv, float* __restrict__ pks)
{
  const int head = blockIdx.x;   // b*H + h, 0..31
  const int split = blockIdx.y;  // 0..S2-1
  const int b = head >> 3, h = head & 7;
  const int tid = threadIdx.x, wv = tid >> 6, d = tid & 63;
  const short* kb = qkv_b + (size_t)b * LL * NQKV + 512 + h * 64;
  const short* vb = qkv_b + (size_t)b * LL * NQKV + 1024 + h * 64 + wv * 16;
  float acc[16];
#pragma unroll
  for (int j = 0; j < 16; ++j) acc[j] = 0.f;
  float ks = 0.f;
  const int l0 = split * (LL / S2);
  for (int li = 0; li < LL / S2; ++li) {
    const size_t ro = (size_t)(l0 + li) * NQKV;
    const float kd = bf2f(kb[ro + d]);
    ks += kd;
    s16x8 v0 = *(const s16x8*)(vb + ro);
    s16x8 v1 = *(const s16x8*)(vb + ro + 8);
#pragma unroll
    for (int j = 0; j < 8; ++j) acc[j] = fmaf(bf2f(v0[j]), kd, acc[j]);
#pragma unroll
    for (int j = 0; j < 8; ++j) acc[8 + j] = fmaf(bf2f(v1[j]), kd, acc[8 + j]);
  }
  float* o = pkv + ((size_t)head * S2 + split) * 4096 + d;
#pragma unroll
  for (int j = 0; j < 16; ++j) o[(wv * 16 + j) * 64] = acc[j];
  if (wv == 0) pks[((size_t)head * S2 + split) * 64 + d] = ks;
}

// reduce partials -> bf16 kv_b [head][m][d], bf16 ksum_b [head][d] (with +1e-6)
__global__ void kv_reduce(const float* __restrict__ pkv, const float* __restrict__ pks,
                          short* __restrict__ kv_b, short* __restrict__ ksum_b)
{
  const int idx = blockIdx.x * 256 + threadIdx.x;   // head*4096 + m*64 + d
  const int head = idx >> 12, md = idx & 4095;
  float s = 0.f;
  for (int i = 0; i < S2; ++i) s += pkv[((size_t)head * S2 + i) * 4096 + md];
  kv_b[idx] = f2bf(s);
  if (md < 64) {
    float t = 0.f;
    for (int i = 0; i < S2; ++i) t += pks[((size_t)head * S2 + i) * 64 + md];
    ksum_b[head * 64 + md] = f2bf(t + 1e-6f);
  }
}

// ---------------- attn via MFMA: attn[l][m] = (q_l . kv[m]) / (q_l . ksum) ----------------
__global__ __launch_bounds__(256, 2)
void attn_mfma(const short* __restrict__ qkv_b, const short* __restrict__ kv_b,
               const short* __restrict__ ksum_b, short* __restrict__ attn)
{
  const int hb = blockIdx.x;     // 0..31 (b*H + h)
  const int tile = blockIdx.y;   // 0..31 (256 rows each)
  const int b = hb >> 3, h = hb & 7;
  const int tid = threadIdx.x, wv = tid >> 6, lane = tid & 63;
  const int fr = lane & 15, fk = (lane >> 4) * 8;

  const short* kvp = kv_b + (size_t)hb * 4096;
  s16x8 bfrag[4][2];
#pragma unroll
  for (int j = 0; j < 4; ++j)
#pragma unroll
    for (int kk = 0; kk < 2; ++kk)
      bfrag[j][kk] = *(const s16x8*)(kvp + (j * 16 + fr) * 64 + kk * 32 + fk);
  s16x8 bden[2];
#pragma unroll
  for (int kk = 0; kk < 2; ++kk)
    bden[kk] = *(const s16x8*)(ksum_b + hb * 64 + kk * 32 + fk);

  const short* qb = qkv_b + (size_t)b * LL * NQKV + h * 64;
  const int l0 = tile * 256 + wv * 64;
  f32x4 accn[4][4] = {};
  f32x4 accd[4] = {};
#pragma unroll
  for (int i = 0; i < 4; ++i) {
#pragma unroll
    for (int kk = 0; kk < 2; ++kk) {
      s16x8 a = *(const s16x8*)(qb + (size_t)(l0 + i * 16 + fr) * NQKV + kk * 32 + fk);
      accd[i] = __builtin_amdgcn_mfma_f32_16x16x32_bf16(a, bden[kk], accd[i], 0, 0, 0);
#pragma unroll
      for (int j = 0; j < 4; ++j)
        accn[i][j] = __builtin_amdgcn_mfma_f32_16x16x32_bf16(a, bfrag[j][kk], accn[i][j], 0, 0, 0);
    }
  }

  short* ob = attn + (size_t)b * LL * DD + h * 64;
  const int fq = lane >> 4;
#pragma unroll
  for (int i = 0; i < 4; ++i) {
#pragma unroll
    for (int r = 0; r < 4; ++r) {
      const int row = l0 + i * 16 + fq * 4 + r;
      const float dinv = 1.0f / accd[i][r];
#pragma unroll
      for (int j = 0; j < 4; ++j) {
        ob[(size_t)row * DD + j * 16 + fr] = f2bf(accn[i][j][r] * dinv);
      }
    }
  }
}

// ---------------- launch ----------------
extern "C" void kernel_launch(void* const* d_in, const int* in_sizes, int n_in,
                              void* d_out, int out_size, void* d_ws, size_t ws_size,
                              hipStream_t stream)
{
  const float* x     = (const float*)d_in[0];
  const float* w_qkv = (const float*)d_in[1];
  const float* b_qkv = (const float*)d_in[2];
  const float* w_out = (const float*)d_in[3];
  const float* b_out = (const float*)d_in[4];

  char* ws = (char*)d_ws;
  size_t off = 0;
  short* x_b   = (short*)(ws + off); off += (size_t)MM * DD * 2;        // 32 MB
  short* wq_t  = (short*)(ws + off); off += (size_t)NQKV * DD * 2;      // 1.5 MB
  short* wo_t  = (short*)(ws + off); off += (size_t)DD * DD * 2;        // 0.5 MB
  short* qkv_b = (short*)(ws + off); off += (size_t)MM * NQKV * 2;      // 96 MB
  short* attn_b= (short*)(ws + off); off += (size_t)MM * DD * 2;        // 32 MB
  float* pkv   = (float*)(ws + off); off += (size_t)32 * S2 * 4096 * 4; // 16 MB
  float* pks   = (float*)(ws + off); off += (size_t)32 * S2 * 64 * 4;   // 0.5 MB
  short* kv_b  = (short*)(ws + off); off += (size_t)32 * 4096 * 2;      // 0.25 MB
  short* ksum_b= (short*)(ws + off); off += (size_t)32 * 64 * 2;        // 4 KB

  conv_bf16<<<dim3((MM * DD / 4 + 255) / 256), dim3(256), 0, stream>>>(x, x_b, MM * DD);
  conv_wt<<<dim3((DD * NQKV + 255) / 256), dim3(256), 0, stream>>>(w_qkv, wq_t, DD, NQKV);
  conv_wt<<<dim3((DD * DD + 255) / 256), dim3(256), 0, stream>>>(w_out, wo_t, DD, DD);

  // qkv = x @ w_qkv + b; phi on q,k; bf16 store
  gemm_bt<NQKV, 0><<<dim3(MM / 256, NQKV / 128), dim3(512), 0, stream>>>(
      x_b, wq_t, b_qkv, (void*)qkv_b);

  kv_partial<<<dim3(32, S2), dim3(256), 0, stream>>>(qkv_b, pkv, pks);
  kv_reduce<<<dim3(512), dim3(256), 0, stream>>>(pkv, pks, kv_b, ksum_b);

  attn_mfma<<<dim3(32, 32), dim3(256), 0, stream>>>(qkv_b, kv_b, ksum_b, attn_b);

  // out = attn @ w_out + b_out (fp32)
  gemm_bt<DD, 1><<<dim3(MM / 256, DD / 128), dim3(512), 0, stream>>>(
      attn_b, wo_t, b_out, d_out);
}

// Round 6
// 171.460 us; speedup vs baseline: 1.5344x; 1.3605x over previous
//
#include <hip/hip_runtime.h>
#include <hip/hip_bf16.h>
#include <math.h>

#define BB 4
#define LL 8192
#define DD 512
#define HH 8
#define MM (BB*LL)      // 32768
#define NQKV 1536
#define CH 32           // K-chunks for kv partial reduction (Kc = 256)

typedef __attribute__((ext_vector_type(4))) float f32x4;
typedef __attribute__((ext_vector_type(8))) short s16x8;
typedef __attribute__((ext_vector_type(4))) short s16x4;

__device__ __forceinline__ float bf2f(short u) {
  union { unsigned int i; float f; } c;
  c.i = ((unsigned int)(unsigned short)u) << 16;
  return c.f;
}
__device__ __forceinline__ short f2bf(float f) {
  union { float f; unsigned int i; } c; c.f = f;
  unsigned int r = c.i + 0x7FFFu + ((c.i >> 16) & 1u);
  return (short)(r >> 16);
}

__device__ __forceinline__ void gload16(const void* g, void* l) {
  __builtin_amdgcn_global_load_lds(
      (const __attribute__((address_space(1))) void*)(g),
      (__attribute__((address_space(3))) void*)(l), 16, 0, 0);
}

// ---------------- conversion kernels ----------------
__global__ void conv_bf16(const float* __restrict__ in, short* __restrict__ out, int n) {
  int i = (blockIdx.x * blockDim.x + threadIdx.x) * 4;
  if (i < n) {
    float4 v = *reinterpret_cast<const float4*>(in + i);
    s16x4 o;
    o[0] = f2bf(v.x); o[1] = f2bf(v.y); o[2] = f2bf(v.z); o[3] = f2bf(v.w);
    *reinterpret_cast<s16x4*>(out + i) = o;
  }
}

// w[K][N] (row-major) -> wt[N][K] bf16
__global__ void conv_wt(const float* __restrict__ w, short* __restrict__ wt, int K, int N) {
  int idx = blockIdx.x * blockDim.x + threadIdx.x;
  if (idx < K * N) {
    int n = idx / K, k = idx - n * K;
    wt[idx] = f2bf(w[(size_t)k * N + n]);
  }
}

// ---------------- bf16 MFMA GEMM, C = A @ BT^T + bias ----------------
// 256x128 tile, BK=64, 8 waves (4M x 2N), per-wave 64x64 out.  48KB staged LDS,
// 64KB epilogue scratch, m-major XCD chunking (A slice = one XCD's 4MB L2).
// Staging swizzle: row r, 16B-unit u stored at (u ^ (r&7)), pre-swizzled source.
// MODE 0 (qkv): q cols -> phi + row-major q_b[M][512];
//               k cols -> phi + per-head transpose kt[head][dh][8192];
//               v cols -> per-head transpose vt[head][m][8192].
// MODE 1: bias -> fp32 row-major, stride 512.
template<int MODE>
__global__ __launch_bounds__(512, 4)
void gemm_bt(const short* __restrict__ A, const short* __restrict__ BT,
             const float* __restrict__ bias, void* __restrict__ Cout,
             short* __restrict__ ktb, short* __restrict__ vtb)
{
  constexpr int KD = 512;
  __shared__ __align__(16) char lds[65536];   // As 32KB | Bs 16KB; epilogue reuses 64KB

  const int tid = threadIdx.x;
  const int wv = tid >> 6, lane = tid & 63;
  const int wm = wv >> 1, wn = wv & 1;        // 4 m-waves x 2 n-waves
  const int fr = lane & 15, fq = lane >> 4;

  // m-major XCD chunking: each XCD owns a contiguous m-stripe
  const int gx = gridDim.x;                   // # m-blocks
  const int gy = gridDim.y;                   // # n-blocks
  const int d = blockIdx.y * gx + blockIdx.x;
  const int nwg = gx * gy;
  const int lin = (d & 7) * (nwg >> 3) + (d >> 3);
  const int m0 = (lin / gy) * 256, n0 = (lin % gy) * 128;

  // staging: rows (tid>>3)+i*64; LDS unit tid&7 holds global unit (tid&7)^(row&7)
  const int srow = tid >> 3;
  const int sunit = (tid & 7) ^ (srow & 7);
  const short* Ag = A  + (size_t)(m0 + srow) * KD + sunit * 8;
  const short* Bg = BT + (size_t)(n0 + srow) * KD + sunit * 8;
  char* ldsw = lds + wv * 1024;               // + lane*16 implicit in gload_lds

  f32x4 acc[4][4] = {};

  for (int t = 0; t < 8; ++t) {
    const int k0 = t * 64;
#pragma unroll
    for (int i = 0; i < 4; ++i)
      gload16(Ag + (size_t)(i * 64) * KD + k0, ldsw + i * 8192);
#pragma unroll
    for (int i = 0; i < 2; ++i)
      gload16(Bg + (size_t)(i * 64) * KD + k0, ldsw + 32768 + i * 8192);
    __syncthreads();
#pragma unroll
    for (int kk = 0; kk < 2; ++kk) {
      s16x8 af[4], bfg[4];
#pragma unroll
      for (int i = 0; i < 4; ++i) {
        const int ra = wm * 64 + i * 16 + fr;
        const int ua = (kk * 4 + fq) ^ (ra & 7);
        af[i] = *(const s16x8*)(lds + ra * 128 + ua * 16);
      }
#pragma unroll
      for (int j = 0; j < 4; ++j) {
        const int rb = wn * 64 + j * 16 + fr;
        const int ub = (kk * 4 + fq) ^ (rb & 7);
        bfg[j] = *(const s16x8*)(lds + 32768 + rb * 128 + ub * 16);
      }
#pragma unroll
      for (int i = 0; i < 4; ++i)
#pragma unroll
        for (int j = 0; j < 4; ++j)
          acc[i][j] = __builtin_amdgcn_mfma_f32_16x16x32_bf16(af[i], bfg[j], acc[i][j], 0, 0, 0);
    }
    __syncthreads();
  }

  // ---- epilogue ----
  if (MODE == 0) {
    if (n0 < 512) {
      // q: phi + row-major bf16 to Cout (q_b), stride 512
      short* scr = (short*)lds;   // 256x128
#pragma unroll
      for (int j = 0; j < 4; ++j) {
        const int col = wn * 64 + j * 16 + fr;
        const float bv = bias[n0 + col];
#pragma unroll
        for (int i = 0; i < 4; ++i) {
          const int row = wm * 64 + i * 16 + fq * 4;
#pragma unroll
          for (int r = 0; r < 4; ++r) {
            float v = acc[i][j][r] + bv;
            v = (v > 0.f) ? (v + 1.f) : __expf(v);   // phi = elu+1
            scr[(row + r) * 128 + col] = f2bf(v);
          }
        }
      }
      __syncthreads();
#pragma unroll
      for (int p = 0; p < 8; ++p) {
        const int off = p * 8192 + tid * 16;          // bytes
        const int row = off >> 8, colb = off & 255;   // 256B per row
        s16x8 v = *(const s16x8*)(lds + off);
        *(s16x8*)((short*)Cout + (size_t)(m0 + row) * 512 + n0 + (colb >> 1)) = v;
      }
    } else {
      // k/v: (phi for k) + per-head transposed write
      const bool do_phi = (n0 < 1024);
      short* tdst = do_phi ? ktb : vtb;
      const int f0 = n0 - (do_phi ? 512 : 1024);
      // write acc -> scr_t[col][l] (col-run = 256 l = 32x16B units),
      // unit u stored at u ^ (col&31)
#pragma unroll
      for (int j = 0; j < 4; ++j) {
        const int col = wn * 64 + j * 16 + fr;
        const float bv = bias[n0 + col];
        const int cx = col & 31;
#pragma unroll
        for (int i = 0; i < 4; ++i) {
          const int l = wm * 64 + i * 16 + fq * 4;
          s16x4 pk;
#pragma unroll
          for (int r = 0; r < 4; ++r) {
            float v = acc[i][j][r] + bv;
            if (do_phi) v = (v > 0.f) ? (v + 1.f) : __expf(v);
            pk[r] = f2bf(v);
          }
          *(s16x4*)(lds + col * 512 + (((l >> 3) ^ cx) * 16) + (l & 7) * 2) = pk;
        }
      }
      __syncthreads();
#pragma unroll
      for (int p = 0; p < 8; ++p) {
        const int g = p * 512 + tid;
        const int col = g >> 5, up = g & 31;
        const int u = up ^ (col & 31);
        s16x8 v = *(const s16x8*)(lds + col * 512 + up * 16);
        const int f = f0 + col;
        const int hb = ((m0 >> 13) << 3) + (f >> 6);
        short* dst = tdst + ((size_t)hb * 64 + (f & 63)) * 8192 + (m0 & 8191) + u * 8;
        *(s16x8*)dst = v;
      }
    }
  } else {
    float* scrf = (float*)lds;  // 128x128 fp32 per half
#pragma unroll
    for (int h = 0; h < 2; ++h) {
      __syncthreads();
      if ((wm >> 1) == h) {
#pragma unroll
        for (int j = 0; j < 4; ++j) {
          const int col = wn * 64 + j * 16 + fr;
          const float bv = bias[n0 + col];
#pragma unroll
          for (int i = 0; i < 4; ++i) {
            const int row = (wm & 1) * 64 + i * 16 + fq * 4;
#pragma unroll
            for (int r = 0; r < 4; ++r)
              scrf[(row + r) * 128 + col] = acc[i][j][r] + bv;
          }
        }
      }
      __syncthreads();
#pragma unroll
      for (int p = 0; p < 8; ++p) {
        const int off = p * 8192 + tid * 16;
        const int row = off >> 9, colb = off & 511;   // 512B per row
        float4 v = *(const float4*)(lds + off);
        *(float4*)((float*)Cout + (size_t)(m0 + h * 128 + row) * 512 + n0 + (colb >> 2)) = v;
      }
    }
  }
}

// ---------------- kv partials via MFMA ----------------
// Per block (head hb, chunk c), Kc=256:
//   pkv[hb][c][m][d] = sum_{l in chunk} vt[hb][m][l] * kt[hb][d][l]
//   pks[hb][c][d]    = sum_{l in chunk} kt[hb][d][l]   (ones-A MFMA, row m=0)
// 4 waves: wave w owns d-quadrant w*16..+15, full m=64.
__global__ __launch_bounds__(256, 4)
void kv_mfma(const short* __restrict__ kt, const short* __restrict__ vt,
             float* __restrict__ pkv, float* __restrict__ pks)
{
  const int hb = blockIdx.x, c = blockIdx.y;
  const int tid = threadIdx.x, wv = tid >> 6, lane = tid & 63;
  const int fr = lane & 15, fq = lane >> 4;
  const size_t base = (size_t)hb * 64 * 8192;
  const int l0 = c * 256;
  const short* vrow = vt + base + (size_t)fr * 8192 + l0 + fq * 8;
  const short* krow = kt + base + (size_t)(wv * 16 + fr) * 8192 + l0 + fq * 8;

  s16x8 ones;
#pragma unroll
  for (int j = 0; j < 8; ++j) ones[j] = (short)0x3F80;   // bf16 1.0

  f32x4 acc[4] = {};
  f32x4 accd = {};
#pragma unroll
  for (int ks = 0; ks < 8; ++ks) {
    s16x8 bfr = *(const s16x8*)(krow + ks * 32);
    accd = __builtin_amdgcn_mfma_f32_16x16x32_bf16(ones, bfr, accd, 0, 0, 0);
#pragma unroll
    for (int i = 0; i < 4; ++i) {
      s16x8 af = *(const s16x8*)(vrow + (size_t)(i * 16) * 8192 + ks * 32);
      acc[i] = __builtin_amdgcn_mfma_f32_16x16x32_bf16(af, bfr, acc[i], 0, 0, 0);
    }
  }
  float* o = pkv + ((size_t)hb * CH + c) * 4096;
#pragma unroll
  for (int i = 0; i < 4; ++i)
#pragma unroll
    for (int r = 0; r < 4; ++r)
      o[(i * 16 + fq * 4 + r) * 64 + wv * 16 + fr] = acc[i][r];
  if (fq == 0)
    pks[((size_t)hb * CH + c) * 64 + wv * 16 + fr] = accd[0];
}

// reduce partials -> bf16 kv_b [head][m][d], bf16 ksum_b [head][d] (with +1e-6)
__global__ void kv_reduce(const float* __restrict__ pkv, const float* __restrict__ pks,
                          short* __restrict__ kv_b, short* __restrict__ ksum_b)
{
  const int idx = blockIdx.x * 256 + threadIdx.x;   // head*4096 + m*64 + d
  const int head = idx >> 12, md = idx & 4095;
  float s = 0.f;
  for (int i = 0; i < CH; ++i) s += pkv[((size_t)head * CH + i) * 4096 + md];
  kv_b[idx] = f2bf(s);
  if (md < 64) {
    float t = 0.f;
    for (int i = 0; i < CH; ++i) t += pks[((size_t)head * CH + i) * 64 + md];
    ksum_b[head * 64 + md] = f2bf(t + 1e-6f);
  }
}

// ---------------- attn via MFMA: attn[l][m] = (q_l . kv[m]) / (q_l . ksum) ----------------
__global__ __launch_bounds__(256, 2)
void attn_mfma(const short* __restrict__ q_b, const short* __restrict__ kv_b,
               const short* __restrict__ ksum_b, short* __restrict__ attn)
{
  const int hb = blockIdx.x;     // 0..31 (b*H + h)
  const int tile = blockIdx.y;   // 0..31 (256 rows each)
  const int b = hb >> 3, h = hb & 7;
  const int tid = threadIdx.x, wv = tid >> 6, lane = tid & 63;
  const int fr = lane & 15, fk = (lane >> 4) * 8;

  const short* kvp = kv_b + (size_t)hb * 4096;
  s16x8 bfrag[4][2];
#pragma unroll
  for (int j = 0; j < 4; ++j)
#pragma unroll
    for (int kk = 0; kk < 2; ++kk)
      bfrag[j][kk] = *(const s16x8*)(kvp + (j * 16 + fr) * 64 + kk * 32 + fk);
  s16x8 bden[2];
#pragma unroll
  for (int kk = 0; kk < 2; ++kk)
    bden[kk] = *(const s16x8*)(ksum_b + hb * 64 + kk * 32 + fk);

  const short* qb = q_b + (size_t)b * LL * DD + h * 64;
  const int l0 = tile * 256 + wv * 64;
  f32x4 accn[4][4] = {};
  f32x4 accd[4] = {};
#pragma unroll
  for (int i = 0; i < 4; ++i) {
#pragma unroll
    for (int kk = 0; kk < 2; ++kk) {
      s16x8 a = *(const s16x8*)(qb + (size_t)(l0 + i * 16 + fr) * DD + kk * 32 + fk);
      accd[i] = __builtin_amdgcn_mfma_f32_16x16x32_bf16(a, bden[kk], accd[i], 0, 0, 0);
#pragma unroll
      for (int j = 0; j < 4; ++j)
        accn[i][j] = __builtin_amdgcn_mfma_f32_16x16x32_bf16(a, bfrag[j][kk], accn[i][j], 0, 0, 0);
    }
  }

  short* ob = attn + (size_t)b * LL * DD + h * 64;
  const int fq = lane >> 4;
#pragma unroll
  for (int i = 0; i < 4; ++i) {
#pragma unroll
    for (int r = 0; r < 4; ++r) {
      const int row = l0 + i * 16 + fq * 4 + r;
      const float dinv = 1.0f / accd[i][r];
#pragma unroll
      for (int j = 0; j < 4; ++j) {
        ob[(size_t)row * DD + j * 16 + fr] = f2bf(accn[i][j][r] * dinv);
      }
    }
  }
}

// ---------------- launch ----------------
extern "C" void kernel_launch(void* const* d_in, const int* in_sizes, int n_in,
                              void* d_out, int out_size, void* d_ws, size_t ws_size,
                              hipStream_t stream)
{
  const float* x     = (const float*)d_in[0];
  const float* w_qkv = (const float*)d_in[1];
  const float* b_qkv = (const float*)d_in[2];
  const float* w_out = (const float*)d_in[3];
  const float* b_out = (const float*)d_in[4];

  char* ws = (char*)d_ws;
  size_t off = 0;
  short* x_b   = (short*)(ws + off); off += (size_t)MM * DD * 2;        // 32 MB
  short* wq_t  = (short*)(ws + off); off += (size_t)NQKV * DD * 2;      // 1.5 MB
  short* wo_t  = (short*)(ws + off); off += (size_t)DD * DD * 2;        // 0.5 MB
  short* q_b   = (short*)(ws + off); off += (size_t)MM * DD * 2;        // 32 MB
  short* kt    = (short*)(ws + off); off += (size_t)32 * 64 * LL * 2;   // 32 MB
  short* vt    = (short*)(ws + off); off += (size_t)32 * 64 * LL * 2;   // 32 MB
  short* attn_b= (short*)(ws + off); off += (size_t)MM * DD * 2;        // 32 MB
  float* pkv   = (float*)(ws + off); off += (size_t)32 * CH * 4096 * 4; // 16 MB
  float* pks   = (float*)(ws + off); off += (size_t)32 * CH * 64 * 4;   // 0.25 MB
  short* kv_b  = (short*)(ws + off); off += (size_t)32 * 4096 * 2;      // 0.25 MB
  short* ksum_b= (short*)(ws + off); off += (size_t)32 * 64 * 2;        // 4 KB

  conv_bf16<<<dim3((MM * DD / 4 + 255) / 256), dim3(256), 0, stream>>>(x, x_b, MM * DD);
  conv_wt<<<dim3((DD * NQKV + 255) / 256), dim3(256), 0, stream>>>(w_qkv, wq_t, DD, NQKV);
  conv_wt<<<dim3((DD * DD + 255) / 256), dim3(256), 0, stream>>>(w_out, wo_t, DD, DD);

  // qkv GEMM: q -> q_b (phi), k -> kt (phi, transposed), v -> vt (transposed)
  gemm_bt<0><<<dim3(MM / 256, NQKV / 128), dim3(512), 0, stream>>>(
      x_b, wq_t, b_qkv, (void*)q_b, kt, vt);

  kv_mfma<<<dim3(32, CH), dim3(256), 0, stream>>>(kt, vt, pkv, pks);
  kv_reduce<<<dim3(512), dim3(256), 0, stream>>>(pkv, pks, kv_b, ksum_b);

  attn_mfma<<<dim3(32, 32), dim3(256), 0, stream>>>(q_b, kv_b, ksum_b, attn_b);

  // out = attn @ w_out + b_out (fp32)
  gemm_bt<1><<<dim3(MM / 256, DD / 128), dim3(512), 0, stream>>>(
      attn_b, wo_t, b_out, d_out, nullptr, nullptr);
}